// Round 5
// baseline (272.375 us; speedup 1.0000x reference)
//
#include <hip/hip_runtime.h>

// Problem constants (from reference)
#define IMG_W 640
#define IMG_H 480
#define BATCH 32
#define HWSZ (IMG_H * IMG_W)          // 307200
#define CHWSZ (3 * HWSZ)              // 921600
#define NPIX (BATCH * HWSZ)           // 9830400

#define ROWS_PER_BLK 2
#define PAIRS_PER_IMG (IMG_H / ROWS_PER_BLK)   // 240
#define NBLOCKS (BATCH * PAIRS_PER_IMG)        // 7680
#define NTHREADS IMG_W                         // 640 threads = 10 waves

// Key identities (exact in the reference's math):
//   V_proj == v  ->  y = 480*v/479 - 0.5 is constant per output row, so the
//   y-interpolation weights wy0/wy1 and source rows are row-uniform.
//   U_proj = u + 80/d  ->  x = U_proj*(640/639) - 0.5, and U_proj >= 1 so
//   only the un > 1 (right-edge) invalidation can trigger.
// Pre-blend: warped(u,c) = mw0*B[e0].c + mw1*B[e1].c with
//   B[x] = wy0m*rowA[x] + wy1m*rowB[x]  (computed once per source column).
// Pack B as float4 {r,g,b,r+g+b} so the validity sum is one FMA pair.
// Pair (v0, v0+1) needs source rows y0s0, y0s0+1, y0s0+2 (floor(y) advances
// by exactly 1 inside every even-aligned pair; the single +2 jump at
// v=239->240 falls on a pair boundary).

__global__ __launch_bounds__(NTHREADS) void photo_main(
    const float* __restrict__ rgb_right,
    const float* __restrict__ rgb_left,
    const float* __restrict__ depth,
    float* __restrict__ partials)
{
    const int bb = blockIdx.x / PAIRS_PER_IMG;
    const int vpair = blockIdx.x - bb * PAIRS_PER_IMG;
    const int v0 = 2 * vpair;
    const int t = threadIdx.x;          // source/output x coordinate, 0..639

    __shared__ float4 bld[ROWS_PER_BLK * IMG_W];  // pre-blended rows
    __shared__ float red[NTHREADS / 64];

    const float* __restrict__ Lb = rgb_left + (size_t)bb * CHWSZ;

    const float yrow0 = (480.0f * (float)v0) / 479.0f - 0.5f;
    const int y0s0 = (int)floorf(yrow0);

    // Load 3 source rows x 3 channels into registers (coalesced dword streams)
    float c[3][3];
#pragma unroll
    for (int k = 0; k < 3; ++k) {
        const int rsrc = min(max(y0s0 + k, 0), IMG_H - 1);
        const float* src = Lb + (size_t)rsrc * IMG_W + t;
        c[k][0] = src[0];
        c[k][1] = src[HWSZ];
        c[k][2] = src[2 * HWSZ];
    }

    // Blend per output row, store packed {r,g,b,sum}
#pragma unroll
    for (int i = 0; i < ROWS_PER_BLK; ++i) {
        const int v = v0 + i;
        const float yrow = (480.0f * (float)v) / 479.0f - 0.5f;
        const int y0i = (int)floorf(yrow);   // == y0s0 + i
        const float wy1 = yrow - (float)y0i;
        const float wy0 = 1.0f - wy1;
        const float wy0m = (y0i >= 0) ? wy0 : 0.0f;
        const float wy1m = (y0i + 1 <= IMG_H - 1) ? wy1 : 0.0f;
        const float br = wy0m * c[i][0] + wy1m * c[i + 1][0];
        const float bg = wy0m * c[i][1] + wy1m * c[i + 1][1];
        const float bbv = wy0m * c[i][2] + wy1m * c[i + 1][2];
        bld[i * IMG_W + t] = make_float4(br, bg, bbv, br + bg + bbv);
    }
    __syncthreads();

    const float uf = (float)t;
    float acc = 0.0f;

#pragma unroll
    for (int i = 0; i < ROWS_PER_BLK; ++i) {
        const int v = v0 + i;
        const size_t pbase = (size_t)bb * HWSZ + (size_t)v * IMG_W + t;
        const size_t cbase = (size_t)bb * CHWSZ + (size_t)v * IMG_W + t;
        const float dd = depth[pbase];
        const float Rr = rgb_right[cbase];
        const float Rg = rgb_right[cbase + HWSZ];
        const float Rb2 = rgb_right[cbase + 2 * HWSZ];

        // x math: U_proj = u + 80/d; x = U_proj*(640/639) - 0.5
        const float rz = __builtin_amdgcn_rcpf(fmaxf(dd, 0.001f));
        const float Up = fmaf(80.0f, rz, uf);
        const bool valid = (Up <= 639.0f);   // un <= 1; un >= -1 always
        const float x = fmaf(Up, 640.0f / 639.0f, -0.5f);
        const float x0f = floorf(x);
        const float wx1 = x - x0f;
        const float wx0 = 1.0f - wx1;
        const int x0 = (int)x0f;
        const int e0 = min(max(x0, 0), IMG_W - 1);
        const int e1 = min(x0 + 1, IMG_W - 1);

        const float mw0 = valid ? wx0 : 0.0f;
        const float mw1 = (valid && (x0 < IMG_W - 1)) ? wx1 : 0.0f;

        // 2 random-x LDS taps (b128 each)
        const float4 b0 = bld[i * IMG_W + e0];
        const float4 b1 = bld[i * IMG_W + e1];

        const float wa = mw0 * b0.x + mw1 * b1.x;
        const float wb = mw0 * b0.y + mw1 * b1.y;
        const float wc = mw0 * b0.z + mw1 * b1.z;
        const float wsum = mw0 * b0.w + mw1 * b1.w;

        const float diff = fabsf(wa - Rr) + fabsf(wb - Rg) + fabsf(wc - Rb2);

        // rgb_left channel-sum > 0 holds w.p. ~1 for uniform(0,255) inputs.
        acc += (wsum > 0.0f) ? diff : 0.0f;
    }

    // wave(64) shuffle reduce, then LDS across 10 waves
    for (int off = 32; off > 0; off >>= 1)
        acc += __shfl_down(acc, off, 64);

    const int lane = threadIdx.x & 63;
    const int wave = threadIdx.x >> 6;
    if (lane == 0) red[wave] = acc;
    __syncthreads();
    if (threadIdx.x == 0) {
        float s = 0.0f;
#pragma unroll
        for (int w = 0; w < NTHREADS / 64; ++w) s += red[w];
        partials[blockIdx.x] = s;
    }
}

__global__ __launch_bounds__(1024) void photo_finish(
    const float* __restrict__ partials,
    float* __restrict__ out,
    int nb)
{
    double s = 0.0;
    for (int i = threadIdx.x; i < nb; i += blockDim.x)
        s += (double)partials[i];

    for (int off = 32; off > 0; off >>= 1)
        s += __shfl_down(s, off, 64);

    __shared__ double lds[16];
    const int lane = threadIdx.x & 63;
    const int wave = threadIdx.x >> 6;
    if (lane == 0) lds[wave] = s;
    __syncthreads();
    if (threadIdx.x == 0) {
        double tt = 0.0;
#pragma unroll
        for (int w = 0; w < 16; ++w) tt += lds[w];
        out[0] = (float)(tt / (double)NPIX);
    }
}

extern "C" void kernel_launch(void* const* d_in, const int* in_sizes, int n_in,
                              void* d_out, int out_size, void* d_ws, size_t ws_size,
                              hipStream_t stream) {
    const float* rgb_right = (const float*)d_in[0];
    const float* rgb_left  = (const float*)d_in[1];
    const float* depth     = (const float*)d_in[2];
    float* partials = (float*)d_ws;
    float* out = (float*)d_out;

    photo_main<<<NBLOCKS, NTHREADS, 0, stream>>>(rgb_right, rgb_left, depth, partials);
    photo_finish<<<1, 1024, 0, stream>>>(partials, out, NBLOCKS);
}